// Round 1
// baseline (1771.763 us; speedup 1.0000x reference)
//
#include <hip/hip_runtime.h>
#include <math.h>

#define TTOK 8192
#define DDIM 1024
#define HDIM 4096
#define NEXP 8
#define NASSIGN (TTOK * 2)

typedef float f32x4 __attribute__((ext_vector_type(4)));
typedef short s16x8 __attribute__((ext_vector_type(8)));

__device__ __forceinline__ unsigned short f2bf(float f) {
  union { float f; unsigned int u; } v; v.f = f;
  unsigned int u = v.u;
  u += 0x7FFFu + ((u >> 16) & 1u);   // RNE
  return (unsigned short)(u >> 16);
}

__device__ __forceinline__ float gelu_tanh(float x) {
  const float k = 0.7978845608028654f;  // sqrt(2/pi)
  float u = k * (x + 0.044715f * x * x * x);
  return 0.5f * x * (1.0f + tanhf(u));
}

// ---- fp32 -> bf16 weight conversion (vectorized) ----
__global__ void cvt_bf16_k(const float* __restrict__ src,
                           unsigned short* __restrict__ dst, int n4) {
  int i = blockIdx.x * blockDim.x + threadIdx.x;
  if (i >= n4) return;
  float4 v = ((const float4*)src)[i];
  ushort4 o;
  o.x = f2bf(v.x); o.y = f2bf(v.y); o.z = f2bf(v.z); o.w = f2bf(v.w);
  ((ushort4*)dst)[i] = o;
}

// ---- router: logits = (x + se[sidx]) @ rw^T + rb ; top-2 + softmax ----
// one wave per token, fp64 accumulation to minimize top-2 tie flips vs ref
__global__ void router_k(const float* __restrict__ x, const float* __restrict__ se,
                         const int* __restrict__ sidx, const float* __restrict__ rw,
                         const float* __restrict__ rb,
                         int* __restrict__ e0, int* __restrict__ e1,
                         float* __restrict__ w0, float* __restrict__ w1,
                         int* __restrict__ counts) {
  int t = blockIdx.x * 4 + (threadIdx.x >> 6);
  int lane = threadIdx.x & 63;
  const float4* xp = (const float4*)(x + (size_t)t * DDIM) + lane * 4;
  const float4* sp = (const float4*)(se + (size_t)sidx[0] * DDIM) + lane * 4;
  float xs[16];
#pragma unroll
  for (int c = 0; c < 4; ++c) {
    float4 a = xp[c], b = sp[c];
    xs[c * 4 + 0] = a.x + b.x; xs[c * 4 + 1] = a.y + b.y;
    xs[c * 4 + 2] = a.z + b.z; xs[c * 4 + 3] = a.w + b.w;
  }
  double acc[NEXP];
#pragma unroll
  for (int e = 0; e < NEXP; ++e) acc[e] = 0.0;
#pragma unroll
  for (int e = 0; e < NEXP; ++e) {
    const float4* wp = (const float4*)(rw + (size_t)e * DDIM) + lane * 4;
#pragma unroll
    for (int c = 0; c < 4; ++c) {
      float4 wv = wp[c];
      acc[e] += (double)xs[c * 4 + 0] * wv.x + (double)xs[c * 4 + 1] * wv.y +
                (double)xs[c * 4 + 2] * wv.z + (double)xs[c * 4 + 3] * wv.w;
    }
  }
#pragma unroll
  for (int e = 0; e < NEXP; ++e) {
#pragma unroll
    for (int m = 32; m >= 1; m >>= 1) acc[e] += __shfl_xor(acc[e], m, 64);
  }
  if (lane == 0) {
    float lg[NEXP];
    for (int e = 0; e < NEXP; ++e) lg[e] = (float)acc[e] + rb[e];
    int i0 = 0; float l0 = lg[0];
    for (int e = 1; e < NEXP; ++e) if (lg[e] > l0) { l0 = lg[e]; i0 = e; }
    int i1 = -1; float l1 = -1e30f;
    for (int e = 0; e < NEXP; ++e) if (e != i0 && lg[e] > l1) { l1 = lg[e]; i1 = e; }
    float z = expf(l1 - l0);
    float p0 = 1.0f / (1.0f + z);
    e0[t] = i0; e1[t] = i1; w0[t] = p0; w1[t] = 1.0f - p0;
    atomicAdd(&counts[i0], 1);
    atomicAdd(&counts[i1], 1);
  }
}

__global__ void scan_k(const int* __restrict__ counts, int* __restrict__ offsets,
                       int* __restrict__ cursors) {
  if (threadIdx.x == 0 && blockIdx.x == 0) {
    int s = 0;
    for (int e = 0; e < NEXP; ++e) { offsets[e] = s; cursors[e] = s; s += counts[e]; }
    offsets[NEXP] = s;
  }
}

__global__ void scatter_k(const int* __restrict__ e0, const int* __restrict__ e1,
                          const float* __restrict__ w0, const float* __restrict__ w1,
                          int* __restrict__ cursors, int* __restrict__ buckets,
                          float* __restrict__ wts) {
  int t = blockIdx.x * blockDim.x + threadIdx.x;
  if (t >= TTOK) return;
  int a = e0[t];
  int p = atomicAdd(&cursors[a], 1);
  buckets[p] = t; wts[p] = w0[t];
  a = e1[t];
  p = atomicAdd(&cursors[a], 1);
  buckets[p] = t; wts[p] = w1[t];
}

// gather token rows (raw x, NOT x+se) into compacted bf16 A matrix
__global__ void gather_k(const float* __restrict__ x, const int* __restrict__ buckets,
                         unsigned short* __restrict__ Xg) {
  int r = blockIdx.x;
  int t = buckets[r];
  int i = threadIdx.x;
  float4 v = ((const float4*)(x + (size_t)t * DDIM))[i];
  ushort4 o;
  o.x = f2bf(v.x); o.y = f2bf(v.y); o.z = f2bf(v.z); o.w = f2bf(v.w);
  ((ushort4*)(Xg + (size_t)r * DDIM))[i] = o;
}

// ---- grouped NT GEMM, m97 structure: 128x128 tile, BK=64, 4 waves x (4x4) 16x16x32 MFMA
// EPI==0: fc1 -> gelu -> bf16 Hout.  EPI==1: fc2 -> (+bias)*wt -> atomicAdd scatter to out.
template <int KD, int ND, int EPI>
__global__ __launch_bounds__(256) void moe_gemm_k(
    const unsigned short* __restrict__ A,   // compacted rows x KD (bf16)
    const unsigned short* __restrict__ W,   // NEXP x ND x KD (bf16)
    const float* __restrict__ bias,         // NEXP x ND
    const int* __restrict__ offsets,        // NEXP+1
    const int* __restrict__ buckets, const float* __restrict__ wts,
    unsigned short* __restrict__ Hout, float* __restrict__ out) {
  const int e = blockIdx.z;
  const int row0 = offsets[e], row1 = offsets[e + 1];
  const int m0 = row0 + blockIdx.x * 128;
  if (m0 >= row1) return;   // uniform per block: safe with barriers below
  const int n0 = blockIdx.y * 128;
  const unsigned short* We = W + (size_t)e * ND * KD;

  __shared__ unsigned short As[128 * 64];
  __shared__ unsigned short Bs[128 * 64];

  const int tid = threadIdx.x;
  const int lane = tid & 63;
  const int w = tid >> 6;
  const int q = lane >> 4;      // quad
  const int c16 = lane & 15;
  const int wrow = (w >> 1) * 64;
  const int wcol = (w & 1) * 64;

  f32x4 acc[4][4];
#pragma unroll
  for (int i = 0; i < 4; ++i)
#pragma unroll
    for (int j = 0; j < 4; ++j) acc[i][j] = {0.f, 0.f, 0.f, 0.f};

  const int srow = w * 8 + (lane >> 3);  // row within 32-row issue group
  const int schunk = lane & 7;           // 16B chunk within 128B row

  for (int kt = 0; kt < KD / 64; ++kt) {
    const int k0 = kt * 64;
    __syncthreads();
#pragma unroll
    for (int i = 0; i < 4; ++i) {
      int ar = m0 + i * 32 + srow;
      if (ar > row1 - 1) ar = row1 - 1;  // clamp: no OOB, garbage rows masked at store
      const unsigned short* ga = A + (size_t)ar * KD + k0 + schunk * 8;
      __builtin_amdgcn_global_load_lds(
          (const __attribute__((address_space(1))) void*)ga,
          (__attribute__((address_space(3))) void*)(As + (i * 32 + w * 8) * 64),
          16, 0, 0);
    }
#pragma unroll
    for (int i = 0; i < 4; ++i) {
      int br = n0 + i * 32 + srow;
      const unsigned short* gb = We + (size_t)br * KD + k0 + schunk * 8;
      __builtin_amdgcn_global_load_lds(
          (const __attribute__((address_space(1))) void*)gb,
          (__attribute__((address_space(3))) void*)(Bs + (i * 32 + w * 8) * 64),
          16, 0, 0);
    }
    __syncthreads();
#pragma unroll
    for (int ks = 0; ks < 2; ++ks) {
      s16x8 af[4], bfr[4];
#pragma unroll
      for (int i = 0; i < 4; ++i)
        af[i] = *((const s16x8*)(As + (wrow + i * 16 + c16) * 64 + ks * 32 + q * 8));
#pragma unroll
      for (int j = 0; j < 4; ++j)
        bfr[j] = *((const s16x8*)(Bs + (wcol + j * 16 + c16) * 64 + ks * 32 + q * 8));
#pragma unroll
      for (int i = 0; i < 4; ++i)
#pragma unroll
        for (int j = 0; j < 4; ++j)
          acc[i][j] = __builtin_amdgcn_mfma_f32_16x16x32_bf16(af[i], bfr[j], acc[i][j], 0, 0, 0);
    }
  }

  // epilogue: C/D layout col=lane&15, row=(lane>>4)*4+reg  [m89/m91-verified]
#pragma unroll
  for (int i = 0; i < 4; ++i) {
#pragma unroll
    for (int r = 0; r < 4; ++r) {
      const int m = m0 + wrow + i * 16 + q * 4 + r;
      if (m < row1) {
        if (EPI == 0) {
#pragma unroll
          for (int j = 0; j < 4; ++j) {
            const int n = n0 + wcol + j * 16 + c16;
            float v = acc[i][j][r] + bias[(size_t)e * ND + n];
            Hout[(size_t)m * ND + n] = f2bf(gelu_tanh(v));
          }
        } else {
          const int t = buckets[m];
          const float sw = wts[m];
          float* op = out + (size_t)t * ND;
#pragma unroll
          for (int j = 0; j < 4; ++j) {
            const int n = n0 + wcol + j * 16 + c16;
            float v = (acc[i][j][r] + bias[(size_t)e * ND + n]) * sw;
            atomicAdd(op + n, v);
          }
        }
      }
    }
  }
}

extern "C" void kernel_launch(void* const* d_in, const int* in_sizes, int n_in,
                              void* d_out, int out_size, void* d_ws, size_t ws_size,
                              hipStream_t stream) {
  const float* x  = (const float*)d_in[0];
  const float* se = (const float*)d_in[1];
  const float* rw = (const float*)d_in[2];
  const float* rb = (const float*)d_in[3];
  const float* w1 = (const float*)d_in[4];
  const float* b1 = (const float*)d_in[5];
  const float* w2 = (const float*)d_in[6];
  const float* b2 = (const float*)d_in[7];
  const int* sidx = (const int*)d_in[8];
  float* out = (float*)d_out;

  char* ws = (char*)d_ws;
  size_t off = 0;
  unsigned short* w1b = (unsigned short*)(ws + off); off += (size_t)NEXP * HDIM * DDIM * 2;  // 64 MB
  unsigned short* w2b = (unsigned short*)(ws + off); off += (size_t)NEXP * DDIM * HDIM * 2;  // 64 MB
  unsigned short* Xg  = (unsigned short*)(ws + off); off += (size_t)NASSIGN * DDIM * 2;      // 32 MB
  unsigned short* Hb  = (unsigned short*)(ws + off); off += (size_t)NASSIGN * HDIM * 2;      // 128 MB
  int*   counts  = (int*)(ws + off); off += 64;
  int*   offsets = (int*)(ws + off); off += 64;
  int*   cursors = (int*)(ws + off); off += 64;
  int*   e0  = (int*)(ws + off);   off += (size_t)TTOK * 4;
  int*   e1  = (int*)(ws + off);   off += (size_t)TTOK * 4;
  float* tw0 = (float*)(ws + off); off += (size_t)TTOK * 4;
  float* tw1 = (float*)(ws + off); off += (size_t)TTOK * 4;
  int*   buckets = (int*)(ws + off); off += (size_t)NASSIGN * 4;
  float* wts = (float*)(ws + off);   off += (size_t)NASSIGN * 4;

  hipMemsetAsync(out, 0, (size_t)TTOK * DDIM * 4, stream);
  hipMemsetAsync(counts, 0, 192, stream);

  const int n4 = NEXP * HDIM * DDIM / 4;
  cvt_bf16_k<<<n4 / 256, 256, 0, stream>>>(w1, w1b, n4);
  cvt_bf16_k<<<n4 / 256, 256, 0, stream>>>(w2, w2b, n4);
  router_k<<<TTOK / 4, 256, 0, stream>>>(x, se, sidx, rw, rb, e0, e1, tw0, tw1, counts);
  scan_k<<<1, 64, 0, stream>>>(counts, offsets, cursors);
  scatter_k<<<TTOK / 256, 256, 0, stream>>>(e0, e1, tw0, tw1, cursors, buckets, wts);
  gather_k<<<NASSIGN, 256, 0, stream>>>(x, buckets, Xg);

  dim3 g1(64, HDIM / 128, NEXP);
  moe_gemm_k<DDIM, HDIM, 0><<<g1, 256, 0, stream>>>(Xg, w1b, b1, offsets, buckets, wts, Hb, out);
  dim3 g2(64, DDIM / 128, NEXP);
  moe_gemm_k<HDIM, DDIM, 1><<<g2, 256, 0, stream>>>(Hb, w2b, b2, offsets, buckets, wts, Hb, out);
}

// Round 2
// 1148.553 us; speedup vs baseline: 1.5426x; 1.5426x over previous
//
#include <hip/hip_runtime.h>
#include <math.h>

#define TTOK 8192
#define DDIM 1024
#define HDIM 4096
#define NEXP 8
#define NASSIGN (TTOK * 2)

typedef float f32x4 __attribute__((ext_vector_type(4)));
typedef short s16x8 __attribute__((ext_vector_type(8)));

__device__ __forceinline__ unsigned short f2bf(float f) {
  union { float f; unsigned int u; } v; v.f = f;
  unsigned int u = v.u;
  u += 0x7FFFu + ((u >> 16) & 1u);   // RNE
  return (unsigned short)(u >> 16);
}

// gelu_tanh(x) = 0.5x(1+tanh(u)) = x * sigmoid(2u),  u = sqrt(2/pi)(x+0.044715x^3)
__device__ __forceinline__ float gelu_fast(float x) {
  float u = 0.7978845608028654f * x * (1.0f + 0.044715f * x * x);
  return x / (1.0f + __expf(-2.0f * u));
}

// ---- fp32 -> bf16 weight conversion (vectorized) ----
__global__ void cvt_bf16_k(const float* __restrict__ src,
                           unsigned short* __restrict__ dst, int n4) {
  int i = blockIdx.x * blockDim.x + threadIdx.x;
  if (i >= n4) return;
  float4 v = ((const float4*)src)[i];
  ushort4 o;
  o.x = f2bf(v.x); o.y = f2bf(v.y); o.z = f2bf(v.z); o.w = f2bf(v.w);
  ((ushort4*)dst)[i] = o;
}

// ---- router: logits = (x + se[sidx]) @ rw^T + rb ; top-2 + softmax ----
__global__ void router_k(const float* __restrict__ x, const float* __restrict__ se,
                         const int* __restrict__ sidx, const float* __restrict__ rw,
                         const float* __restrict__ rb,
                         int* __restrict__ e0, int* __restrict__ e1,
                         float* __restrict__ w0, float* __restrict__ w1,
                         int* __restrict__ counts) {
  int t = blockIdx.x * 4 + (threadIdx.x >> 6);
  int lane = threadIdx.x & 63;
  const float4* xp = (const float4*)(x + (size_t)t * DDIM) + lane * 4;
  const float4* sp = (const float4*)(se + (size_t)sidx[0] * DDIM) + lane * 4;
  float xs[16];
#pragma unroll
  for (int c = 0; c < 4; ++c) {
    float4 a = xp[c], b = sp[c];
    xs[c * 4 + 0] = a.x + b.x; xs[c * 4 + 1] = a.y + b.y;
    xs[c * 4 + 2] = a.z + b.z; xs[c * 4 + 3] = a.w + b.w;
  }
  double acc[NEXP];
#pragma unroll
  for (int e = 0; e < NEXP; ++e) acc[e] = 0.0;
#pragma unroll
  for (int e = 0; e < NEXP; ++e) {
    const float4* wp = (const float4*)(rw + (size_t)e * DDIM) + lane * 4;
#pragma unroll
    for (int c = 0; c < 4; ++c) {
      float4 wv = wp[c];
      acc[e] += (double)xs[c * 4 + 0] * wv.x + (double)xs[c * 4 + 1] * wv.y +
                (double)xs[c * 4 + 2] * wv.z + (double)xs[c * 4 + 3] * wv.w;
    }
  }
#pragma unroll
  for (int e = 0; e < NEXP; ++e) {
#pragma unroll
    for (int m = 32; m >= 1; m >>= 1) acc[e] += __shfl_xor(acc[e], m, 64);
  }
  if (lane == 0) {
    float lg[NEXP];
    for (int e = 0; e < NEXP; ++e) lg[e] = (float)acc[e] + rb[e];
    int i0 = 0; float l0 = lg[0];
    for (int e = 1; e < NEXP; ++e) if (lg[e] > l0) { l0 = lg[e]; i0 = e; }
    int i1 = -1; float l1 = -1e30f;
    for (int e = 0; e < NEXP; ++e) if (e != i0 && lg[e] > l1) { l1 = lg[e]; i1 = e; }
    float z = expf(l1 - l0);
    float p0 = 1.0f / (1.0f + z);
    e0[t] = i0; e1[t] = i1; w0[t] = p0; w1[t] = 1.0f - p0;
    atomicAdd(&counts[i0], 1);
    atomicAdd(&counts[i1], 1);
  }
}

// prefix-scan + build m-tile table (<=135 entries of {m0, row1, e, 0})
__global__ void scan_k(const int* __restrict__ counts, int* __restrict__ offsets,
                       int* __restrict__ cursors, int4* __restrict__ tileT,
                       int* __restrict__ ntiles) {
  if (threadIdx.x == 0 && blockIdx.x == 0) {
    int s = 0;
    for (int e = 0; e < NEXP; ++e) { offsets[e] = s; cursors[e] = s; s += counts[e]; }
    offsets[NEXP] = s;
    int nt = 0;
    for (int e = 0; e < NEXP; ++e)
      for (int m0 = offsets[e]; m0 < offsets[e + 1]; m0 += 128)
        tileT[nt++] = make_int4(m0, offsets[e + 1], e, 0);
    ntiles[0] = nt;
  }
}

__global__ void scatter_k(const int* __restrict__ e0, const int* __restrict__ e1,
                          const float* __restrict__ w0, const float* __restrict__ w1,
                          int* __restrict__ cursors, int* __restrict__ buckets,
                          float* __restrict__ wts, int* __restrict__ s0,
                          int* __restrict__ s1) {
  int t = blockIdx.x * blockDim.x + threadIdx.x;
  if (t >= TTOK) return;
  int a = e0[t];
  int p = atomicAdd(&cursors[a], 1);
  buckets[p] = t; wts[p] = w0[t]; s0[t] = p;
  a = e1[t];
  p = atomicAdd(&cursors[a], 1);
  buckets[p] = t; wts[p] = w1[t]; s1[t] = p;
}

// gather token rows (raw x) into compacted bf16 A matrix
__global__ void gather_k(const float* __restrict__ x, const int* __restrict__ buckets,
                         unsigned short* __restrict__ Xg) {
  int r = blockIdx.x;
  int t = buckets[r];
  int i = threadIdx.x;
  float4 v = ((const float4*)(x + (size_t)t * DDIM))[i];
  ushort4 o;
  o.x = f2bf(v.x); o.y = f2bf(v.y); o.z = f2bf(v.z); o.w = f2bf(v.w);
  ((ushort4*)(Xg + (size_t)r * DDIM))[i] = o;
}

// ---- persistent grouped NT GEMM, 128x128 tile, BK=64, XOR-swizzled LDS ----
// EPI==0: fc1 -> gelu -> bf16 Hout.   EPI==1: fc2 -> (+bias) -> f32 rows in Yout.
template <int KD, int ND, int EPI>
__global__ __launch_bounds__(256) void moe_gemm_k(
    const unsigned short* __restrict__ A,   // compacted slots x KD (bf16)
    const unsigned short* __restrict__ W,   // NEXP x ND x KD (bf16)
    const float* __restrict__ bias,         // NEXP x ND
    const int4* __restrict__ tileT, const int* __restrict__ ntiles,
    unsigned short* __restrict__ Hout, float* __restrict__ Yout) {
  constexpr int NT = ND / 128;
  __shared__ unsigned short As[128 * 64];
  __shared__ unsigned short Bs[128 * 64];

  const int tid = threadIdx.x;
  const int lane = tid & 63;
  const int w = tid >> 6;
  const int q = lane >> 4;      // quad
  const int c16 = lane & 15;
  const int cx = lane & 7;      // = c16 & 7, read-side swizzle key
  const int wrow = (w >> 1) * 64;
  const int wcol = (w & 1) * 64;
  const int srow = w * 8 + (lane >> 3);          // staging row in 32-row group
  const int swz = (lane & 7) ^ (lane >> 3);      // swizzled global chunk for this lane

  const int total = ntiles[0] * NT;              // uniform across block

  for (int tt = blockIdx.x; tt < total; tt += gridDim.x) {
    const int mt = tt / NT;
    const int nb = tt - mt * NT;
    const int4 tl = tileT[mt];
    const int m0 = tl.x, row1 = tl.y, e = tl.z;
    const int n0 = nb * 128;
    const unsigned short* We = W + (size_t)e * ND * KD;

    f32x4 acc[4][4];
#pragma unroll
    for (int i = 0; i < 4; ++i)
#pragma unroll
      for (int j = 0; j < 4; ++j) acc[i][j] = {0.f, 0.f, 0.f, 0.f};

    for (int kt = 0; kt < KD / 64; ++kt) {
      const int k0 = kt * 64;
      __syncthreads();
#pragma unroll
      for (int i = 0; i < 4; ++i) {
        int ar = m0 + i * 32 + srow;
        if (ar > row1 - 1) ar = row1 - 1;  // clamp: garbage rows masked at store
        const unsigned short* ga = A + (size_t)ar * KD + k0 + swz * 8;
        __builtin_amdgcn_global_load_lds(
            (const __attribute__((address_space(1))) void*)ga,
            (__attribute__((address_space(3))) void*)(As + (i * 32 + w * 8) * 64),
            16, 0, 0);
      }
#pragma unroll
      for (int i = 0; i < 4; ++i) {
        int br = n0 + i * 32 + srow;
        const unsigned short* gb = We + (size_t)br * KD + k0 + swz * 8;
        __builtin_amdgcn_global_load_lds(
            (const __attribute__((address_space(1))) void*)gb,
            (__attribute__((address_space(3))) void*)(Bs + (i * 32 + w * 8) * 64),
            16, 0, 0);
      }
      __syncthreads();
#pragma unroll
      for (int ks = 0; ks < 2; ++ks) {
        s16x8 af[4], bfr[4];
#pragma unroll
        for (int i = 0; i < 4; ++i)
          af[i] = *((const s16x8*)(As + (wrow + i * 16 + c16) * 64 +
                                   (((ks * 4 + q) ^ cx) * 8)));
#pragma unroll
        for (int j = 0; j < 4; ++j)
          bfr[j] = *((const s16x8*)(Bs + (wcol + j * 16 + c16) * 64 +
                                    (((ks * 4 + q) ^ cx) * 8)));
#pragma unroll
        for (int i = 0; i < 4; ++i)
#pragma unroll
          for (int j = 0; j < 4; ++j)
            acc[i][j] = __builtin_amdgcn_mfma_f32_16x16x32_bf16(af[i], bfr[j], acc[i][j], 0, 0, 0);
      }
    }

    // epilogue: C/D layout col=lane&15, row=(lane>>4)*4+reg  [m89/m91-verified]
    float bj[4];
#pragma unroll
    for (int j = 0; j < 4; ++j)
      bj[j] = bias[(size_t)e * ND + n0 + wcol + j * 16 + c16];
#pragma unroll
    for (int i = 0; i < 4; ++i) {
#pragma unroll
      for (int r = 0; r < 4; ++r) {
        const int m = m0 + wrow + i * 16 + q * 4 + r;
        if (m < row1) {
          if (EPI == 0) {
#pragma unroll
            for (int j = 0; j < 4; ++j) {
              const int n = n0 + wcol + j * 16 + c16;
              Hout[(size_t)m * ND + n] = f2bf(gelu_fast(acc[i][j][r] + bj[j]));
            }
          } else {
#pragma unroll
            for (int j = 0; j < 4; ++j) {
              const int n = n0 + wcol + j * 16 + c16;
              Yout[(size_t)m * ND + n] = acc[i][j][r] + bj[j];
            }
          }
        }
      }
    }
  }
}

// out[t] = w(s0)*Y[s0[t]] + w(s1)*Y[s1[t]]
__global__ void combine_k(const float* __restrict__ Yr, const int* __restrict__ s0,
                          const int* __restrict__ s1, const float* __restrict__ wts,
                          float* __restrict__ out) {
  int t = blockIdx.x;
  int i = threadIdx.x;
  int a = s0[t], b = s1[t];
  float wa = wts[a], wb = wts[b];
  float4 va = ((const float4*)(Yr + (size_t)a * DDIM))[i];
  float4 vb = ((const float4*)(Yr + (size_t)b * DDIM))[i];
  float4 o;
  o.x = wa * va.x + wb * vb.x;
  o.y = wa * va.y + wb * vb.y;
  o.z = wa * va.z + wb * vb.z;
  o.w = wa * va.w + wb * vb.w;
  ((float4*)(out + (size_t)t * DDIM))[i] = o;
}

extern "C" void kernel_launch(void* const* d_in, const int* in_sizes, int n_in,
                              void* d_out, int out_size, void* d_ws, size_t ws_size,
                              hipStream_t stream) {
  const float* x  = (const float*)d_in[0];
  const float* se = (const float*)d_in[1];
  const float* rw = (const float*)d_in[2];
  const float* rb = (const float*)d_in[3];
  const float* w1 = (const float*)d_in[4];
  const float* b1 = (const float*)d_in[5];
  const float* w2 = (const float*)d_in[6];
  const float* b2 = (const float*)d_in[7];
  const int* sidx = (const int*)d_in[8];
  float* out = (float*)d_out;

  char* ws = (char*)d_ws;
  size_t off = 0;
  unsigned short* w1b = (unsigned short*)(ws + off); off += (size_t)NEXP * HDIM * DDIM * 2;  // 64 MB
  unsigned short* w2b = (unsigned short*)(ws + off); off += (size_t)NEXP * DDIM * HDIM * 2;  // 64 MB
  unsigned short* Xg  = (unsigned short*)(ws + off); off += (size_t)NASSIGN * DDIM * 2;      // 32 MB
  unsigned short* Hb  = (unsigned short*)(ws + off); off += (size_t)NASSIGN * HDIM * 2;      // 128 MB
  float* Yr = (float*)w1b;  // 64 MB, overlays w1b (dead after fc1)
  int*   counts  = (int*)(ws + off); off += 64;
  int*   offsets = (int*)(ws + off); off += 64;
  int*   cursors = (int*)(ws + off); off += 64;
  int*   ntiles  = (int*)(ws + off); off += 64;
  int*   e0  = (int*)(ws + off);   off += (size_t)TTOK * 4;
  int*   e1  = (int*)(ws + off);   off += (size_t)TTOK * 4;
  float* tw0 = (float*)(ws + off); off += (size_t)TTOK * 4;
  float* tw1 = (float*)(ws + off); off += (size_t)TTOK * 4;
  int*   s0  = (int*)(ws + off);   off += (size_t)TTOK * 4;
  int*   s1  = (int*)(ws + off);   off += (size_t)TTOK * 4;
  int*   buckets = (int*)(ws + off); off += (size_t)NASSIGN * 4;
  float* wts = (float*)(ws + off);   off += (size_t)NASSIGN * 4;
  int4*  tileT = (int4*)(ws + off);  off += 256 * 16;

  hipMemsetAsync(counts, 0, 64, stream);

  const int n4 = NEXP * HDIM * DDIM / 4;
  cvt_bf16_k<<<n4 / 256, 256, 0, stream>>>(w1, w1b, n4);
  cvt_bf16_k<<<n4 / 256, 256, 0, stream>>>(w2, w2b, n4);
  router_k<<<TTOK / 4, 256, 0, stream>>>(x, se, sidx, rw, rb, e0, e1, tw0, tw1, counts);
  scan_k<<<1, 64, 0, stream>>>(counts, offsets, cursors, tileT, ntiles);
  scatter_k<<<TTOK / 256, 256, 0, stream>>>(e0, e1, tw0, tw1, cursors, buckets, wts, s0, s1);
  gather_k<<<NASSIGN, 256, 0, stream>>>(x, buckets, Xg);

  moe_gemm_k<DDIM, HDIM, 0><<<1024, 256, 0, stream>>>(Xg, w1b, b1, tileT, ntiles, Hb, Yr);
  moe_gemm_k<HDIM, DDIM, 1><<<1024, 256, 0, stream>>>(Hb, w2b, b2, tileT, ntiles, Hb, Yr);
  combine_k<<<TTOK, 256, 0, stream>>>(Yr, s0, s1, wts, out);
}

// Round 3
// 1145.069 us; speedup vs baseline: 1.5473x; 1.0030x over previous
//
#include <hip/hip_runtime.h>
#include <math.h>

#define TTOK 8192
#define DDIM 1024
#define HDIM 4096
#define NEXP 8
#define NASSIGN (TTOK * 2)

typedef float f32x4 __attribute__((ext_vector_type(4)));
typedef short s16x8 __attribute__((ext_vector_type(8)));

__device__ __forceinline__ unsigned short f2bf(float f) {
  union { float f; unsigned int u; } v; v.f = f;
  unsigned int u = v.u;
  u += 0x7FFFu + ((u >> 16) & 1u);   // RNE
  return (unsigned short)(u >> 16);
}

// gelu_tanh(x) = 0.5x(1+tanh(u)) = x * sigmoid(2u),  u = sqrt(2/pi)(x+0.044715x^3)
__device__ __forceinline__ float gelu_fast(float x) {
  float u = 0.7978845608028654f * x * (1.0f + 0.044715f * x * x);
  return x / (1.0f + __expf(-2.0f * u));
}

// ---- fp32 -> bf16 conversion of BOTH weight tensors, one launch, 2 float4/thread ----
__global__ void cvt_bf16_k(const float* __restrict__ w1, unsigned short* __restrict__ w1b,
                           const float* __restrict__ w2, unsigned short* __restrict__ w2b,
                           int n8) {  // n8 = float8-chunks per tensor
  int i = blockIdx.x * blockDim.x + threadIdx.x;
  const float* src; unsigned short* dst;
  if (i < n8) { src = w1; dst = w1b; } else { src = w2; dst = w2b; i -= n8; }
#pragma unroll
  for (int c = 0; c < 2; ++c) {
    float4 v = ((const float4*)src)[i * 2 + c];
    ushort4 o;
    o.x = f2bf(v.x); o.y = f2bf(v.y); o.z = f2bf(v.z); o.w = f2bf(v.w);
    ((ushort4*)dst)[i * 2 + c] = o;
  }
}

// ---- router: logits = (x + se[sidx]) @ rw^T + rb ; top-2 + softmax ----
__global__ void router_k(const float* __restrict__ x, const float* __restrict__ se,
                         const int* __restrict__ sidx, const float* __restrict__ rw,
                         const float* __restrict__ rb,
                         int* __restrict__ e0, int* __restrict__ e1,
                         float* __restrict__ w0, float* __restrict__ w1,
                         int* __restrict__ counts) {
  int t = blockIdx.x * 4 + (threadIdx.x >> 6);
  int lane = threadIdx.x & 63;
  const float4* xp = (const float4*)(x + (size_t)t * DDIM) + lane * 4;
  const float4* sp = (const float4*)(se + (size_t)sidx[0] * DDIM) + lane * 4;
  float xs[16];
#pragma unroll
  for (int c = 0; c < 4; ++c) {
    float4 a = xp[c], b = sp[c];
    xs[c * 4 + 0] = a.x + b.x; xs[c * 4 + 1] = a.y + b.y;
    xs[c * 4 + 2] = a.z + b.z; xs[c * 4 + 3] = a.w + b.w;
  }
  double acc[NEXP];
#pragma unroll
  for (int e = 0; e < NEXP; ++e) acc[e] = 0.0;
#pragma unroll
  for (int e = 0; e < NEXP; ++e) {
    const float4* wp = (const float4*)(rw + (size_t)e * DDIM) + lane * 4;
#pragma unroll
    for (int c = 0; c < 4; ++c) {
      float4 wv = wp[c];
      acc[e] += (double)xs[c * 4 + 0] * wv.x + (double)xs[c * 4 + 1] * wv.y +
                (double)xs[c * 4 + 2] * wv.z + (double)xs[c * 4 + 3] * wv.w;
    }
  }
#pragma unroll
  for (int e = 0; e < NEXP; ++e) {
#pragma unroll
    for (int m = 32; m >= 1; m >>= 1) acc[e] += __shfl_xor(acc[e], m, 64);
  }
  if (lane == 0) {
    float lg[NEXP];
    for (int e = 0; e < NEXP; ++e) lg[e] = (float)acc[e] + rb[e];
    int i0 = 0; float l0 = lg[0];
    for (int e = 1; e < NEXP; ++e) if (lg[e] > l0) { l0 = lg[e]; i0 = e; }
    int i1 = -1; float l1 = -1e30f;
    for (int e = 0; e < NEXP; ++e) if (e != i0 && lg[e] > l1) { l1 = lg[e]; i1 = e; }
    float z = expf(l1 - l0);
    float p0 = 1.0f / (1.0f + z);
    e0[t] = i0; e1[t] = i1; w0[t] = p0; w1[t] = 1.0f - p0;
    atomicAdd(&counts[i0], 1);
    atomicAdd(&counts[i1], 1);
  }
}

// prefix-scan + build m-tile table (<=135 entries of {m0, row1, e, 0})
__global__ void scan_k(const int* __restrict__ counts, int* __restrict__ offsets,
                       int* __restrict__ cursors, int4* __restrict__ tileT,
                       int* __restrict__ ntiles) {
  if (threadIdx.x == 0 && blockIdx.x == 0) {
    int s = 0;
    for (int e = 0; e < NEXP; ++e) { offsets[e] = s; cursors[e] = s; s += counts[e]; }
    offsets[NEXP] = s;
    int nt = 0;
    for (int e = 0; e < NEXP; ++e)
      for (int m0 = offsets[e]; m0 < offsets[e + 1]; m0 += 128)
        tileT[nt++] = make_int4(m0, offsets[e + 1], e, 0);
    ntiles[0] = nt;
  }
}

__global__ void scatter_k(const int* __restrict__ e0, const int* __restrict__ e1,
                          const float* __restrict__ w0, const float* __restrict__ w1,
                          int* __restrict__ cursors, int* __restrict__ buckets,
                          float* __restrict__ wts, int* __restrict__ s0,
                          int* __restrict__ s1) {
  int t = blockIdx.x * blockDim.x + threadIdx.x;
  if (t >= TTOK) return;
  int a = e0[t];
  int p = atomicAdd(&cursors[a], 1);
  buckets[p] = t; wts[p] = w0[t]; s0[t] = p;
  a = e1[t];
  p = atomicAdd(&cursors[a], 1);
  buckets[p] = t; wts[p] = w1[t]; s1[t] = p;
}

// gather token rows (raw x) into compacted bf16 A matrix
__global__ void gather_k(const float* __restrict__ x, const int* __restrict__ buckets,
                         unsigned short* __restrict__ Xg) {
  int r = blockIdx.x;
  int t = buckets[r];
  int i = threadIdx.x;
  float4 v = ((const float4*)(x + (size_t)t * DDIM))[i];
  ushort4 o;
  o.x = f2bf(v.x); o.y = f2bf(v.y); o.z = f2bf(v.z); o.w = f2bf(v.w);
  ((ushort4*)(Xg + (size_t)r * DDIM))[i] = o;
}

// ---- persistent grouped NT GEMM, 128x128 tile, BK=64, XOR-swizzled LDS ----
// XCD-pinned n-columns: xcd = bid&7 owns n-blocks [xcd*G, xcd*G+G); m-tiles swept
// in lockstep across XCDs so A re-reads cluster (LLC hits) and W stays in XCD L2.
// EPI==0: fc1 -> gelu -> bf16 Hout.   EPI==1: fc2 -> (+bias) -> f32 rows in Yout.
template <int KD, int ND, int EPI>
__global__ __launch_bounds__(256) void moe_gemm_k(
    const unsigned short* __restrict__ A,   // compacted slots x KD (bf16)
    const unsigned short* __restrict__ W,   // NEXP x ND x KD (bf16)
    const float* __restrict__ bias,         // NEXP x ND
    const int4* __restrict__ tileT, const int* __restrict__ ntiles,
    unsigned short* __restrict__ Hout, float* __restrict__ Yout) {
  constexpr int NT = ND / 128;
  constexpr int G = NT / 8;                  // n-blocks per XCD
  __shared__ unsigned short As[128 * 64];
  __shared__ unsigned short Bs[128 * 64];

  const int tid = threadIdx.x;
  const int lane = tid & 63;
  const int w = tid >> 6;
  const int q = lane >> 4;      // quad
  const int c16 = lane & 15;
  const int cx = lane & 7;      // read-side swizzle key
  const int wrow = (w >> 1) * 64;
  const int wcol = (w & 1) * 64;
  const int srow = w * 8 + (lane >> 3);          // staging row in 32-row group
  const int swz = (lane & 7) ^ (lane >> 3);      // swizzled global chunk for this lane

  const int xcd = blockIdx.x & 7;
  const int lid = blockIdx.x >> 3;               // 0..255 within XCD group
  const int bound = ntiles[0] * G;               // uniform across block

  for (int idx = lid; idx < bound; idx += 256) {
    const int mt = idx / G;
    const int nb = xcd * G + (idx - mt * G);
    const int4 tl = tileT[mt];
    const int m0 = tl.x, row1 = tl.y, e = tl.z;
    const int n0 = nb * 128;
    const unsigned short* We = W + (size_t)e * ND * KD;

    // hoist clamped row base pointers out of the K-loop
    const unsigned short* aptr[4];
    const unsigned short* bptr[4];
#pragma unroll
    for (int i = 0; i < 4; ++i) {
      int ar = m0 + i * 32 + srow;
      if (ar > row1 - 1) ar = row1 - 1;  // clamp: garbage rows masked at store
      aptr[i] = A + (size_t)ar * KD + swz * 8;
      bptr[i] = We + (size_t)(n0 + i * 32 + srow) * KD + swz * 8;
    }

    f32x4 acc[4][4];
#pragma unroll
    for (int i = 0; i < 4; ++i)
#pragma unroll
      for (int j = 0; j < 4; ++j) acc[i][j] = {0.f, 0.f, 0.f, 0.f};

    for (int kt = 0; kt < KD / 64; ++kt) {
      const int k0 = kt * 64;
      __syncthreads();
#pragma unroll
      for (int i = 0; i < 4; ++i)
        __builtin_amdgcn_global_load_lds(
            (const __attribute__((address_space(1))) void*)(aptr[i] + k0),
            (__attribute__((address_space(3))) void*)(As + (i * 32 + w * 8) * 64),
            16, 0, 0);
#pragma unroll
      for (int i = 0; i < 4; ++i)
        __builtin_amdgcn_global_load_lds(
            (const __attribute__((address_space(1))) void*)(bptr[i] + k0),
            (__attribute__((address_space(3))) void*)(Bs + (i * 32 + w * 8) * 64),
            16, 0, 0);
      __syncthreads();
#pragma unroll
      for (int ks = 0; ks < 2; ++ks) {
        s16x8 af[4], bfr[4];
#pragma unroll
        for (int i = 0; i < 4; ++i)
          af[i] = *((const s16x8*)(As + (wrow + i * 16 + c16) * 64 +
                                   (((ks * 4 + q) ^ cx) * 8)));
#pragma unroll
        for (int j = 0; j < 4; ++j)
          bfr[j] = *((const s16x8*)(Bs + (wcol + j * 16 + c16) * 64 +
                                    (((ks * 4 + q) ^ cx) * 8)));
#pragma unroll
        for (int i = 0; i < 4; ++i)
#pragma unroll
          for (int j = 0; j < 4; ++j)
            acc[i][j] = __builtin_amdgcn_mfma_f32_16x16x32_bf16(af[i], bfr[j], acc[i][j], 0, 0, 0);
      }
    }

    // epilogue: C/D layout col=lane&15, row=(lane>>4)*4+reg  [m89/m91-verified]
    float bj[4];
#pragma unroll
    for (int j = 0; j < 4; ++j)
      bj[j] = bias[(size_t)e * ND + n0 + wcol + j * 16 + c16];
#pragma unroll
    for (int i = 0; i < 4; ++i) {
#pragma unroll
      for (int r = 0; r < 4; ++r) {
        const int m = m0 + wrow + i * 16 + q * 4 + r;
        if (m < row1) {
          if (EPI == 0) {
#pragma unroll
            for (int j = 0; j < 4; ++j) {
              const int n = n0 + wcol + j * 16 + c16;
              Hout[(size_t)m * ND + n] = f2bf(gelu_fast(acc[i][j][r] + bj[j]));
            }
          } else {
#pragma unroll
            for (int j = 0; j < 4; ++j) {
              const int n = n0 + wcol + j * 16 + c16;
              Yout[(size_t)m * ND + n] = acc[i][j][r] + bj[j];
            }
          }
        }
      }
    }
  }
}

// out[t] = w(s0)*Y[s0[t]] + w(s1)*Y[s1[t]]
__global__ void combine_k(const float* __restrict__ Yr, const int* __restrict__ s0,
                          const int* __restrict__ s1, const float* __restrict__ wts,
                          float* __restrict__ out) {
  int t = blockIdx.x;
  int i = threadIdx.x;
  int a = s0[t], b = s1[t];
  float wa = wts[a], wb = wts[b];
  float4 va = ((const float4*)(Yr + (size_t)a * DDIM))[i];
  float4 vb = ((const float4*)(Yr + (size_t)b * DDIM))[i];
  float4 o;
  o.x = wa * va.x + wb * vb.x;
  o.y = wa * va.y + wb * vb.y;
  o.z = wa * va.z + wb * vb.z;
  o.w = wa * va.w + wb * vb.w;
  ((float4*)(out + (size_t)t * DDIM))[i] = o;
}

extern "C" void kernel_launch(void* const* d_in, const int* in_sizes, int n_in,
                              void* d_out, int out_size, void* d_ws, size_t ws_size,
                              hipStream_t stream) {
  const float* x  = (const float*)d_in[0];
  const float* se = (const float*)d_in[1];
  const float* rw = (const float*)d_in[2];
  const float* rb = (const float*)d_in[3];
  const float* w1 = (const float*)d_in[4];
  const float* b1 = (const float*)d_in[5];
  const float* w2 = (const float*)d_in[6];
  const float* b2 = (const float*)d_in[7];
  const int* sidx = (const int*)d_in[8];
  float* out = (float*)d_out;

  char* ws = (char*)d_ws;
  size_t off = 0;
  unsigned short* w1b = (unsigned short*)(ws + off); off += (size_t)NEXP * HDIM * DDIM * 2;  // 64 MB
  unsigned short* w2b = (unsigned short*)(ws + off); off += (size_t)NEXP * DDIM * HDIM * 2;  // 64 MB
  unsigned short* Xg  = (unsigned short*)(ws + off); off += (size_t)NASSIGN * DDIM * 2;      // 32 MB
  unsigned short* Hb  = (unsigned short*)(ws + off); off += (size_t)NASSIGN * HDIM * 2;      // 128 MB
  float* Yr = (float*)w1b;  // 64 MB, overlays w1b (dead after fc1)
  int*   counts  = (int*)(ws + off); off += 64;
  int*   offsets = (int*)(ws + off); off += 64;
  int*   cursors = (int*)(ws + off); off += 64;
  int*   ntiles  = (int*)(ws + off); off += 64;
  int*   e0  = (int*)(ws + off);   off += (size_t)TTOK * 4;
  int*   e1  = (int*)(ws + off);   off += (size_t)TTOK * 4;
  float* tw0 = (float*)(ws + off); off += (size_t)TTOK * 4;
  float* tw1 = (float*)(ws + off); off += (size_t)TTOK * 4;
  int*   s0  = (int*)(ws + off);   off += (size_t)TTOK * 4;
  int*   s1  = (int*)(ws + off);   off += (size_t)TTOK * 4;
  int*   buckets = (int*)(ws + off); off += (size_t)NASSIGN * 4;
  float* wts = (float*)(ws + off);   off += (size_t)NASSIGN * 4;
  int4*  tileT = (int4*)(ws + off);  off += 256 * 16;

  hipMemsetAsync(counts, 0, 64, stream);

  const int n8 = NEXP * HDIM * DDIM / 8;
  cvt_bf16_k<<<2 * n8 / 256, 256, 0, stream>>>(w1, w1b, w2, w2b, n8);
  router_k<<<TTOK / 4, 256, 0, stream>>>(x, se, sidx, rw, rb, e0, e1, tw0, tw1, counts);
  scan_k<<<1, 64, 0, stream>>>(counts, offsets, cursors, tileT, ntiles);
  scatter_k<<<TTOK / 256, 256, 0, stream>>>(e0, e1, tw0, tw1, cursors, buckets, wts, s0, s1);
  gather_k<<<NASSIGN, 256, 0, stream>>>(x, buckets, Xg);

  moe_gemm_k<DDIM, HDIM, 0><<<2048, 256, 0, stream>>>(Xg, w1b, b1, tileT, ntiles, Hb, Yr);
  moe_gemm_k<HDIM, DDIM, 1><<<2048, 256, 0, stream>>>(Hb, w2b, b2, tileT, ntiles, Hb, Yr);
  combine_k<<<TTOK, 256, 0, stream>>>(Yr, s0, s1, wts, out);
}